// Round 1
// baseline (122.783 us; speedup 1.0000x reference)
//
#include <hip/hip_runtime.h>
#include <math.h>

#define N_LOC 16384
#define W 128
#define B_SZ 64
#define D_CTRL 1024
#define TOTAL_OUT 390   // 3*W + 6

__device__ __forceinline__ float dot4(float4 a, float4 b) {
    return a.x * b.x + a.y * b.y + a.z * b.z + a.w * b.w;
}

__device__ __forceinline__ float softplus_f(float x) {
    return fmaxf(x, 0.0f) + log1pf(expf(-fabsf(x)));
}

__device__ __forceinline__ float wave_reduce_sum(float v) {
#pragma unroll
    for (int off = 32; off >= 1; off >>= 1) v += __shfl_xor(v, off);
    return v;
}

__device__ __forceinline__ float wave_reduce_max(float v) {
#pragma unroll
    for (int off = 32; off >= 1; off >>= 1) v = fmaxf(v, __shfl_xor(v, off));
    return v;
}

// ---------------------------------------------------------------------------
// K1: raw[b][o] = cs[b] . fc_w[o] + fc_b[o]
// grid (13 o-chunks, 8 b-tiles), block 256. 8 cs rows staged in LDS.
// ---------------------------------------------------------------------------
__global__ __launch_bounds__(256) void k1_fc(const float* __restrict__ cs,
                                             const float* __restrict__ fcw,
                                             const float* __restrict__ fcb,
                                             float* __restrict__ raw) {
    __shared__ float4 cs4[8][256];
    const int t = threadIdx.x;
    const int oc = blockIdx.x;      // 0..12, 30 outputs each
    const int btile = blockIdx.y;   // 0..7, 8 b each

    const float4* csg = reinterpret_cast<const float4*>(cs);
#pragma unroll
    for (int i = 0; i < 8; i++) {
        int f4 = t + 256 * i;
        int row = f4 >> 8;
        int col = f4 & 255;
        cs4[row][col] = csg[(btile * 8 + row) * 256 + col];
    }
    __syncthreads();

    const int lane = t & 63;
    const int wv = t >> 6;
    const float4* fcw4 = reinterpret_cast<const float4*>(fcw);

    for (int ol = wv; ol < 30; ol += 4) {
        const int o = oc * 30 + ol;
        float4 r0 = fcw4[o * 256 + 0 * 64 + lane];
        float4 r1 = fcw4[o * 256 + 1 * 64 + lane];
        float4 r2 = fcw4[o * 256 + 2 * 64 + lane];
        float4 r3 = fcw4[o * 256 + 3 * 64 + lane];
#pragma unroll
        for (int b = 0; b < 8; b++) {
            float acc = dot4(cs4[b][0 * 64 + lane], r0);
            acc += dot4(cs4[b][1 * 64 + lane], r1);
            acc += dot4(cs4[b][2 * 64 + lane], r2);
            acc += dot4(cs4[b][3 * 64 + lane], r3);
            acc = wave_reduce_sum(acc);
            if (lane == 0) {
                raw[(btile * 8 + b) * TOTAL_OUT + o] = acc + fcb[o];
            }
        }
    }
}

// ---------------------------------------------------------------------------
// K1b: activations. grid 64 (one per b), block 128 (one per w-element).
// keyb = beta * key / max(||key||, 1e-12)  (beta folded in)
// ---------------------------------------------------------------------------
__global__ __launch_bounds__(128) void k1b_act(const float* __restrict__ raw,
                                               float* __restrict__ keyb,
                                               float* __restrict__ erase,
                                               float* __restrict__ addv,
                                               float* __restrict__ gate,
                                               float* __restrict__ shift,
                                               float* __restrict__ gamma) {
    const int b = blockIdx.x;
    const int k = threadIdx.x;
    const float* rb = raw + b * TOTAL_OUT;
    __shared__ float red[2];

    float key = rb[k];
    float ss = wave_reduce_sum(key * key);
    if ((k & 63) == 0) red[k >> 6] = ss;
    __syncthreads();
    float tot = red[0] + red[1];
    float inv = 1.0f / fmaxf(sqrtf(tot), 1e-12f);
    float beta = softplus_f(rb[W]);

    keyb[b * W + k] = beta * key * inv;
    erase[b * W + k] = 1.0f / (1.0f + expf(-rb[W + 6 + k]));
    addv[b * W + k] = tanhf(rb[2 * W + 6 + k]);

    if (k == 0) {
        gate[b] = 1.0f / (1.0f + expf(-rb[W + 1]));
        gamma[b] = softplus_f(rb[W + 5]) + 1.0f;
        float s0 = rb[W + 2], s1 = rb[W + 3], s2 = rb[W + 4];
        float m = fmaxf(s0, fmaxf(s1, s2));
        float e0 = expf(s0 - m), e1 = expf(s1 - m), e2 = expf(s2 - m);
        float si = 1.0f / (e0 + e1 + e2);
        shift[b * 3 + 0] = e0 * si;
        shift[b * 3 + 1] = e1 * si;
        shift[b * 3 + 2] = e2 * si;
    }
}

// ---------------------------------------------------------------------------
// K3: scores[b][n] = keyb[b] . mem[n] / max(||mem[n]||, 1e-12)
// grid 256 (64 n each), block 512 (8 waves x 8 b each). mem tile XOR-swizzled
// float4 in LDS; row norms computed in-LDS; keyb via wave-uniform loads.
// ---------------------------------------------------------------------------
__global__ __launch_bounds__(512) void k3_scores(const float* __restrict__ mem,
                                                 const float* __restrict__ keyb,
                                                 float* __restrict__ scores) {
    __shared__ float4 m4[64][32];
    __shared__ float rn[64];
    const int t = threadIdx.x;
    const int n0 = blockIdx.x * 64;

    const float4* memg = reinterpret_cast<const float4*>(mem) + n0 * 32;
#pragma unroll
    for (int i = 0; i < 4; i++) {
        int f4 = t + 512 * i;
        int row = f4 >> 5;
        int c4 = f4 & 31;
        m4[row][c4 ^ (row & 7)] = memg[f4];
    }
    __syncthreads();

    {   // row norms: 8 threads per row
        int row = t >> 3;
        int s8 = t & 7;
        float acc = 0.0f;
#pragma unroll
        for (int jj = 0; jj < 4; jj++) {
            float4 v = m4[row][(s8 * 4 + jj) ^ (row & 7)];
            acc += v.x * v.x + v.y * v.y + v.z * v.z + v.w * v.w;
        }
        acc += __shfl_xor(acc, 1);
        acc += __shfl_xor(acc, 2);
        acc += __shfl_xor(acc, 4);
        if (s8 == 0) rn[row] = 1.0f / fmaxf(sqrtf(acc), 1e-12f);
    }
    __syncthreads();

    const int lane = t & 63;   // = n_local
    const int wv = t >> 6;     // 0..7
    const float r = rn[lane];
    const float4* kb4 = reinterpret_cast<const float4*>(keyb);

#pragma unroll
    for (int bi = 0; bi < 8; bi++) {
        const int b = wv * 8 + bi;
        float acc = 0.0f;
#pragma unroll
        for (int k4 = 0; k4 < 32; k4++) {
            float4 kb = kb4[b * 32 + k4];           // wave-uniform -> s_load
            float4 mv = m4[lane][k4 ^ (lane & 7)];  // conflict-minimal ds_read_b128
            acc += dot4(kb, mv);
        }
        scores[b * N_LOC + n0 + lane] = acc * r;
    }
}

// ---------------------------------------------------------------------------
// K4: per-row softmax -> gate -> circular shift -> sharpen -> w_new
// grid 64 (one per b), block 1024, 16 items/thread. w_g in 64 KB LDS.
// Reduction scratch reuses wg[] (exactly at 64 KB static LDS limit).
// ---------------------------------------------------------------------------
__device__ __forceinline__ float block_reduce(float v, bool is_max, float* sm, int t) {
#pragma unroll
    for (int off = 32; off >= 1; off >>= 1) {
        float o = __shfl_xor(v, off);
        v = is_max ? fmaxf(v, o) : (v + o);
    }
    __syncthreads();               // scratch region free for reuse
    if ((t & 63) == 0) sm[t >> 6] = v;
    __syncthreads();
    if (t == 0) {
        float r = sm[0];
        for (int i = 1; i < 16; i++) r = is_max ? fmaxf(r, sm[i]) : (r + sm[i]);
        sm[0] = r;
    }
    __syncthreads();
    v = sm[0];
    __syncthreads();               // everyone read before scratch reused
    return v;
}

__global__ __launch_bounds__(1024) void k4_row(const float* __restrict__ scores,
                                               const float* __restrict__ wprev,
                                               const float* __restrict__ gate_,
                                               const float* __restrict__ shift_,
                                               const float* __restrict__ gamma_,
                                               float* __restrict__ wnew) {
    __shared__ float wg[N_LOC];    // 64 KB, doubles as reduce scratch
    const int b = blockIdx.x;
    const int t = threadIdx.x;

    const float gate = gate_[b];
    const float gm = gamma_[b];
    const float sh0 = shift_[b * 3 + 0];
    const float sh1 = shift_[b * 3 + 1];
    const float sh2 = shift_[b * 3 + 2];
    const float* sc = scores + (size_t)b * N_LOC;
    const float* wp = wprev + (size_t)b * N_LOC;

    float s[16];
    float mloc = -INFINITY;
#pragma unroll
    for (int i = 0; i < 16; i++) {
        s[i] = sc[t + 1024 * i];
        mloc = fmaxf(mloc, s[i]);
    }
    const float M = block_reduce(mloc, true, wg, t);

    float sl = 0.0f;
#pragma unroll
    for (int i = 0; i < 16; i++) {
        s[i] = __expf(s[i] - M);
        sl += s[i];
    }
    const float S = block_reduce(sl, false, wg, t);

    const float ga = gate / S;
    const float og = 1.0f - gate;
#pragma unroll
    for (int i = 0; i < 16; i++) {
        int idx = t + 1024 * i;
        float w = ga * s[i] + og * wp[idx];
        wg[idx] = w;
        s[i] = w;
    }
    __syncthreads();

    float sp = 0.0f;
    float p[16];
#pragma unroll
    for (int i = 0; i < 16; i++) {
        int idx = t + 1024 * i;
        float l = wg[(idx + N_LOC - 1) & (N_LOC - 1)];
        float rr = wg[(idx + 1) & (N_LOC - 1)];
        float wsft = sh0 * l + sh1 * s[i] + sh2 * rr;
        float x = fmaxf(wsft, 1e-9f);
        p[i] = exp2f(gm * log2f(x));
        sp += p[i];
    }
    __syncthreads();               // all neighbor reads done; wg reusable
    const float S2 = block_reduce(sp, false, wg, t);

    const float invs = 1.0f / (S2 + 1e-9f);
    float* out = wnew + (size_t)b * N_LOC;
#pragma unroll
    for (int i = 0; i < 16; i++) {
        out[t + 1024 * i] = p[i] * invs;
    }
}

// ---------------------------------------------------------------------------
// K5: new_mem[n][w] = mem[n][w]*(1 - em[n][w]) + am[n][w],
//     em/am = (1/64) sum_b wnew[b][n]*{erase,add}[b][w]
// grid 1024 (16 n each), block 256 (128 w x 2 n-halves), 8 n per thread.
// ---------------------------------------------------------------------------
__global__ __launch_bounds__(256) void k5_update(const float* __restrict__ wnew,
                                                 const float* __restrict__ erase,
                                                 const float* __restrict__ addv,
                                                 const float* __restrict__ mem,
                                                 float* __restrict__ outmem) {
    const int t = threadIdx.x;
    const int w = t & 127;
    const int nh = t >> 7;
    const int nb = blockIdx.x * 16 + nh * 8;

    float ae[8], aa[8];
#pragma unroll
    for (int i = 0; i < 8; i++) { ae[i] = 0.0f; aa[i] = 0.0f; }

    for (int b = 0; b < B_SZ; b++) {
        float we = erase[b * W + w];
        float wa = addv[b * W + w];
        const float* wr = wnew + (size_t)b * N_LOC + nb;   // wave-uniform
#pragma unroll
        for (int i = 0; i < 8; i++) {
            float wv = wr[i];
            ae[i] += wv * we;
            aa[i] += wv * wa;
        }
    }

    const float inv_b = 1.0f / 64.0f;
#pragma unroll
    for (int i = 0; i < 8; i++) {
        int n = nb + i;
        float em = ae[i] * inv_b;
        float am = aa[i] * inv_b;
        float mv = mem[n * W + w];
        outmem[n * W + w] = mv * (1.0f - em) + am;
    }
}

// ---------------------------------------------------------------------------
extern "C" void kernel_launch(void* const* d_in, const int* in_sizes, int n_in,
                              void* d_out, int out_size, void* d_ws, size_t ws_size,
                              hipStream_t stream) {
    const float* cs    = (const float*)d_in[0];   // (64, 1024)
    const float* mem   = (const float*)d_in[1];   // (16384, 128)
    const float* wprev = (const float*)d_in[2];   // (64, 16384)
    const float* fcw   = (const float*)d_in[3];   // (390, 1024)
    const float* fcb   = (const float*)d_in[4];   // (390,)

    float* out = (float*)d_out;
    float* wnew_out = out;                               // (64, 16384)
    float* mem_out = out + (size_t)B_SZ * N_LOC;         // (16384, 128)
    // scores live in the new_memory region of d_out until K5 overwrites it
    // (K4, the only reader, runs before K5 on the same stream).
    float* scores = mem_out;                             // (64, 16384)

    float* wsf = (float*)d_ws;
    float* raw   = wsf;             // 64*390 = 24960
    float* keyb  = raw + 24960;     // 8192  (16B-aligned: 24960*4 % 16 == 0)
    float* erase = keyb + 8192;     // 8192
    float* addv  = erase + 8192;    // 8192
    float* gate  = addv + 8192;     // 64
    float* shift = gate + 64;       // 192
    float* gamma = shift + 192;     // 64   -> total 49856 floats (~200 KB)

    k1_fc<<<dim3(13, 8), 256, 0, stream>>>(cs, fcw, fcb, raw);
    k1b_act<<<64, 128, 0, stream>>>(raw, keyb, erase, addv, gate, shift, gamma);
    k3_scores<<<256, 512, 0, stream>>>(mem, keyb, scores);
    k4_row<<<64, 1024, 0, stream>>>(scores, wprev, gate, shift, gamma, wnew_out);
    k5_update<<<1024, 256, 0, stream>>>(wnew_out, erase, addv, mem, mem_out);
}

// Round 3
// 79.311 us; speedup vs baseline: 1.5481x; 1.5481x over previous
//
#include <hip/hip_runtime.h>
#include <math.h>

#define N_LOC 16384
#define W 128
#define B_SZ 64
#define D_CTRL 1024
#define TOTAL_OUT 390   // 3*W + 6

__device__ __forceinline__ float dot4(float4 a, float4 b) {
    return a.x * b.x + a.y * b.y + a.z * b.z + a.w * b.w;
}

__device__ __forceinline__ float softplus_f(float x) {
    return fmaxf(x, 0.0f) + log1pf(expf(-fabsf(x)));
}

__device__ __forceinline__ float wave_reduce_sum(float v) {
#pragma unroll
    for (int off = 32; off >= 1; off >>= 1) v += __shfl_xor(v, off);
    return v;
}

// ---------------------------------------------------------------------------
// K1: raw[b][o] = cs[b] . fc_w[o] + fc_b[o]
// grid (13 o-chunks, 8 b-tiles), block 256. 8 cs rows staged in LDS.
// ---------------------------------------------------------------------------
__global__ __launch_bounds__(256) void k1_fc(const float* __restrict__ cs,
                                             const float* __restrict__ fcw,
                                             const float* __restrict__ fcb,
                                             float* __restrict__ raw) {
    __shared__ float4 cs4[8][256];
    const int t = threadIdx.x;
    const int oc = blockIdx.x;      // 0..12, 30 outputs each
    const int btile = blockIdx.y;   // 0..7, 8 b each

    const float4* csg = reinterpret_cast<const float4*>(cs);
#pragma unroll
    for (int i = 0; i < 8; i++) {
        int f4 = t + 256 * i;
        int row = f4 >> 8;
        int col = f4 & 255;
        cs4[row][col] = csg[(btile * 8 + row) * 256 + col];
    }
    __syncthreads();

    const int lane = t & 63;
    const int wv = t >> 6;
    const float4* fcw4 = reinterpret_cast<const float4*>(fcw);

    for (int ol = wv; ol < 30; ol += 4) {
        const int o = oc * 30 + ol;
        float4 r0 = fcw4[o * 256 + 0 * 64 + lane];
        float4 r1 = fcw4[o * 256 + 1 * 64 + lane];
        float4 r2 = fcw4[o * 256 + 2 * 64 + lane];
        float4 r3 = fcw4[o * 256 + 3 * 64 + lane];
#pragma unroll
        for (int b = 0; b < 8; b++) {
            float acc = dot4(cs4[b][0 * 64 + lane], r0);
            acc += dot4(cs4[b][1 * 64 + lane], r1);
            acc += dot4(cs4[b][2 * 64 + lane], r2);
            acc += dot4(cs4[b][3 * 64 + lane], r3);
            acc = wave_reduce_sum(acc);
            if (lane == 0) {
                raw[(btile * 8 + b) * TOTAL_OUT + o] = acc + fcb[o];
            }
        }
    }
}

// ---------------------------------------------------------------------------
// K1b: activations. grid 64 (one per b), block 128.
// keyb = beta * key / max(||key||, 1e-12); also emits beta (score upper bound)
// ---------------------------------------------------------------------------
__global__ __launch_bounds__(128) void k1b_act(const float* __restrict__ raw,
                                               float* __restrict__ keyb,
                                               float* __restrict__ erase,
                                               float* __restrict__ addv,
                                               float* __restrict__ gate,
                                               float* __restrict__ shift,
                                               float* __restrict__ gamma,
                                               float* __restrict__ beta_out) {
    const int b = blockIdx.x;
    const int k = threadIdx.x;
    const float* rb = raw + b * TOTAL_OUT;
    __shared__ float red[2];

    float key = rb[k];
    float ss = wave_reduce_sum(key * key);
    if ((k & 63) == 0) red[k >> 6] = ss;
    __syncthreads();
    float tot = red[0] + red[1];
    float inv = 1.0f / fmaxf(sqrtf(tot), 1e-12f);
    float beta = softplus_f(rb[W]);

    keyb[b * W + k] = beta * key * inv;
    erase[b * W + k] = 1.0f / (1.0f + expf(-rb[W + 6 + k]));
    addv[b * W + k] = tanhf(rb[2 * W + 6 + k]);

    if (k == 0) {
        gate[b] = 1.0f / (1.0f + expf(-rb[W + 1]));
        gamma[b] = softplus_f(rb[W + 5]) + 1.0f;
        beta_out[b] = beta;
        float s0 = rb[W + 2], s1 = rb[W + 3], s2 = rb[W + 4];
        float m = fmaxf(s0, fmaxf(s1, s2));
        float e0 = expf(s0 - m), e1 = expf(s1 - m), e2 = expf(s2 - m);
        float si = 1.0f / (e0 + e1 + e2);
        shift[b * 3 + 0] = e0 * si;
        shift[b * 3 + 1] = e1 * si;
        shift[b * 3 + 2] = e2 * si;
    }
}

// ---------------------------------------------------------------------------
// K3: scores[b][n] = keyb[b].mem[n] / max(||mem[n]||,1e-12)
// grid 512 (32 n each), block 256 = 32 n x 8 b-groups (8 b each).
// keyb in LDS, read at (half-)wave-uniform addresses -> conflict-free
// broadcast. mem rows read directly from global: lane-sequential 64B-line
// reuse across k4 iterations keeps them L1-resident. Row norm fused.
// ---------------------------------------------------------------------------
__global__ __launch_bounds__(256) void k3_scores(const float* __restrict__ mem,
                                                 const float* __restrict__ keyb,
                                                 float* __restrict__ scores) {
    __shared__ float4 kb4[B_SZ][32];   // 32 KB
    const int t = threadIdx.x;

    const float4* kg = reinterpret_cast<const float4*>(keyb);
    float4* kbp = reinterpret_cast<float4*>(kb4);
#pragma unroll
    for (int i = 0; i < 8; i++) kbp[t + 256 * i] = kg[t + 256 * i];
    __syncthreads();

    const int n = blockIdx.x * 32 + (t & 31);
    const int bg = t >> 5;             // 0..7 -> b = bg*8 + bi
    const float4* mrow = reinterpret_cast<const float4*>(mem) + (size_t)n * 32;

    float acc[8];
#pragma unroll
    for (int i = 0; i < 8; i++) acc[i] = 0.0f;
    float nrm = 0.0f;

#pragma unroll 8
    for (int k4 = 0; k4 < 32; k4++) {
        float4 mv = mrow[k4];
        nrm += dot4(mv, mv);
#pragma unroll
        for (int bi = 0; bi < 8; bi++) {
            acc[bi] += dot4(kb4[bg * 8 + bi][k4], mv);
        }
    }

    const float r = 1.0f / fmaxf(sqrtf(nrm), 1e-12f);
#pragma unroll
    for (int bi = 0; bi < 8; bi++) {
        scores[(size_t)(bg * 8 + bi) * N_LOC + n] = acc[bi] * r;
    }
}

// ---------------------------------------------------------------------------
// K4: per-row softmax (max-free: scores <= beta exactly) -> gate -> circular
// shift -> sharpen -> w_new. grid 64, block 1024, 16 items/thread.
// w_g in 64 KB LDS (doubles as reduce scratch).
// ---------------------------------------------------------------------------
__device__ __forceinline__ float block_reduce_sum(float v, float* sm, int t) {
#pragma unroll
    for (int off = 32; off >= 1; off >>= 1) v += __shfl_xor(v, off);
    __syncthreads();               // scratch region free for reuse
    if ((t & 63) == 0) sm[t >> 6] = v;
    __syncthreads();
    if (t < 64) {
        float r = (t < 16) ? sm[t] : 0.0f;
#pragma unroll
        for (int off = 8; off >= 1; off >>= 1) r += __shfl_xor(r, off);
        if (t == 0) sm[0] = r;
    }
    __syncthreads();
    v = sm[0];
    __syncthreads();               // everyone read before scratch reused
    return v;
}

__global__ __launch_bounds__(1024) void k4_row(const float* __restrict__ scores,
                                               const float* __restrict__ wprev,
                                               const float* __restrict__ gate_,
                                               const float* __restrict__ shift_,
                                               const float* __restrict__ gamma_,
                                               const float* __restrict__ beta_,
                                               float* __restrict__ wnew) {
    __shared__ float wg[N_LOC];    // 64 KB, doubles as reduce scratch
    const int b = blockIdx.x;
    const int t = threadIdx.x;

    const float gate = gate_[b];
    const float gm = gamma_[b];
    const float M = beta_[b];      // exact upper bound of the row's scores
    const float sh0 = shift_[b * 3 + 0];
    const float sh1 = shift_[b * 3 + 1];
    const float sh2 = shift_[b * 3 + 2];
    const float* sc = scores + (size_t)b * N_LOC;
    const float* wp = wprev + (size_t)b * N_LOC;

    float s[16];
    float sl = 0.0f;
#pragma unroll
    for (int i = 0; i < 16; i++) {
        s[i] = __expf(sc[t + 1024 * i] - M);
        sl += s[i];
    }
    const float S = block_reduce_sum(sl, wg, t);

    const float ga = gate / S;
    const float og = 1.0f - gate;
#pragma unroll
    for (int i = 0; i < 16; i++) {
        int idx = t + 1024 * i;
        float w = ga * s[i] + og * wp[idx];
        wg[idx] = w;
        s[i] = w;
    }
    __syncthreads();

    float sp = 0.0f;
    float p[16];
#pragma unroll
    for (int i = 0; i < 16; i++) {
        int idx = t + 1024 * i;
        float l = wg[(idx + N_LOC - 1) & (N_LOC - 1)];
        float rr = wg[(idx + 1) & (N_LOC - 1)];
        float wsft = sh0 * l + sh1 * s[i] + sh2 * rr;
        float x = fmaxf(wsft, 1e-9f);
        p[i] = exp2f(gm * __log2f(x));
        sp += p[i];
    }
    __syncthreads();               // all neighbor reads done; wg reusable
    const float S2 = block_reduce_sum(sp, wg, t);

    const float invs = 1.0f / (S2 + 1e-9f);
    float* out = wnew + (size_t)b * N_LOC;
#pragma unroll
    for (int i = 0; i < 16; i++) {
        out[t + 1024 * i] = p[i] * invs;
    }
}

// ---------------------------------------------------------------------------
// K5: new_mem[n][w] = mem[n][w]*(1 - em[n][w]) + am[n][w],
//     em/am = (1/64) sum_b wnew[b][n]*{erase,add}[b][w]
// grid 1024 (16 n each), block 256 (128 w x 2 n-halves), 8 n per thread.
// ---------------------------------------------------------------------------
__global__ __launch_bounds__(256) void k5_update(const float* __restrict__ wnew,
                                                 const float* __restrict__ erase,
                                                 const float* __restrict__ addv,
                                                 const float* __restrict__ mem,
                                                 float* __restrict__ outmem) {
    const int t = threadIdx.x;
    const int w = t & 127;
    const int nh = t >> 7;
    const int nb = blockIdx.x * 16 + nh * 8;

    float ae[8], aa[8];
#pragma unroll
    for (int i = 0; i < 8; i++) { ae[i] = 0.0f; aa[i] = 0.0f; }

    for (int b = 0; b < B_SZ; b++) {
        float we = erase[b * W + w];
        float wa = addv[b * W + w];
        const float* wr = wnew + (size_t)b * N_LOC + nb;   // wave-uniform
#pragma unroll
        for (int i = 0; i < 8; i++) {
            float wv = wr[i];
            ae[i] += wv * we;
            aa[i] += wv * wa;
        }
    }

    const float inv_b = 1.0f / 64.0f;
#pragma unroll
    for (int i = 0; i < 8; i++) {
        int n = nb + i;
        float em = ae[i] * inv_b;
        float am = aa[i] * inv_b;
        float mv = mem[n * W + w];
        outmem[n * W + w] = mv * (1.0f - em) + am;
    }
}

// ---------------------------------------------------------------------------
extern "C" void kernel_launch(void* const* d_in, const int* in_sizes, int n_in,
                              void* d_out, int out_size, void* d_ws, size_t ws_size,
                              hipStream_t stream) {
    const float* cs    = (const float*)d_in[0];   // (64, 1024)
    const float* mem   = (const float*)d_in[1];   // (16384, 128)
    const float* wprev = (const float*)d_in[2];   // (64, 16384)
    const float* fcw   = (const float*)d_in[3];   // (390, 1024)
    const float* fcb   = (const float*)d_in[4];   // (390,)

    float* out = (float*)d_out;
    float* wnew_out = out;                               // (64, 16384)
    float* mem_out = out + (size_t)B_SZ * N_LOC;         // (16384, 128)
    // scores live in the new_memory region of d_out until K5 overwrites it
    // (K4, the only reader, runs before K5 on the same stream).
    float* scores = mem_out;                             // (64, 16384)

    float* wsf = (float*)d_ws;
    float* raw   = wsf;             // 64*390 = 24960
    float* keyb  = raw + 24960;     // 8192  (16B-aligned)
    float* erase = keyb + 8192;     // 8192
    float* addv  = erase + 8192;    // 8192
    float* gate  = addv + 8192;     // 64
    float* shift = gate + 64;       // 192
    float* gamma = shift + 192;     // 64
    float* beta  = gamma + 64;      // 64

    k1_fc<<<dim3(13, 8), 256, 0, stream>>>(cs, fcw, fcb, raw);
    k1b_act<<<64, 128, 0, stream>>>(raw, keyb, erase, addv, gate, shift, gamma, beta);
    k3_scores<<<512, 256, 0, stream>>>(mem, keyb, scores);
    k4_row<<<64, 1024, 0, stream>>>(scores, wprev, gate, shift, gamma, beta, wnew_out);
    k5_update<<<1024, 256, 0, stream>>>(wnew_out, erase, addv, mem, mem_out);
}